// Round 11
// baseline (202.406 us; speedup 1.0000x reference)
//
#include <hip/hip_runtime.h>
#include <hip/hip_bf16.h>
#include <stdint.h>
#include <stddef.h>

// Problem: B=2, L=2048, D=1024, H=16, HD=64.
// Inputs FP32, output FP32.  Internal pipeline bf16 MFMA.
// R11: gemm is tile-refetch-BW bound (64 FLOP/byte needs 13.7 TB/s at 874 TF;
// default bid%8 XCD round-robin scatters reuse -> all fetch from L3 ~4 TB/s
// -> 277 TF).  XCD swizzle: each XCD owns 4 m-strips (A L2-hot), sweeps n.
// attn: f2bf RNE (~5 insts) -> +0x8000>>16 (2 insts) for P packs; /9 staging
// maps hoisted out of j0 loop.  R10 lesson: posted stores don't stall — the
// v-epilogue fix was neutral; kept anyway (request-rate hygiene).

#define NB     2
#define NH     16
#define SL     2048
#define DH     64
#define DMODEL 1024
#define SCP    4096   // padded scores row stride (floats); 4095 real
#define CTS    136    // epilogue LDS row stride (shorts)

typedef __attribute__((ext_vector_type(8)))  short bf16x8;
typedef __attribute__((ext_vector_type(4)))  short bf16x4;
typedef __attribute__((ext_vector_type(4)))  float f32x4;
typedef __attribute__((ext_vector_type(16))) float f32x16;

static __device__ __forceinline__ short f2bf(float x) {   // RNE (prep only)
  __hip_bfloat16 h = __float2bfloat16(x);
  return *reinterpret_cast<short*>(&h);
}
static __device__ __forceinline__ short f2bf_fast(float x) {  // round-half-up, 2 insts
  union { float f; uint32_t u; } v; v.f = x;
  return (short)((v.u + 0x8000u) >> 16);
}
static __device__ __forceinline__ long long bf4_to_ll(bf16x4 v) {
  long long r; __builtin_memcpy(&r, &v, 8); return r;
}
static __device__ __forceinline__ bf16x4 ll_to_bf4(long long v) {
  bf16x4 r; __builtin_memcpy(&r, &v, 8); return r;
}
#define GLD(g, l) __builtin_amdgcn_global_load_lds( \
    (const __attribute__((address_space(1))) void*)(g), \
    (__attribute__((address_space(3))) void*)(l), 16, 0, 0)

// ---------------------------------------------------- prep: cvt x, cvt w, bias
__global__ __launch_bounds__(256) void prep_k(
    const float* __restrict__ x, const float* __restrict__ w,
    const float* __restrict__ koff, const float* __restrict__ kamp,
    const float* __restrict__ kshp,
    short* __restrict__ xbf, short* __restrict__ wbf,
    float* __restrict__ scores) {
  const int bx = blockIdx.x, tid = threadIdx.x;
  if (bx < 7168) {
    const float* src = (bx < 4096) ? x : w;
    short* dst       = (bx < 4096) ? xbf : wbf;
    const int i      = (bx < 4096 ? bx : bx - 4096) * 256 + tid;
    float4 a = *(const float4*)(src + (size_t)i * 4);
    bf16x4 o;
    o.x = f2bf(a.x); o.y = f2bf(a.y); o.z = f2bf(a.z); o.w = f2bf(a.w);
    *(bf16x4*)(dst + (size_t)i * 4) = o;
  } else {
    const int idx = bx - 7168;
    const int h = idx >> 4;
    const int r = (idx & 15) * 256 + tid;
    if (r >= 4095) return;
    float rel = (float)(r - (SL - 1));
    float acc = 0.f;
#pragma unroll
    for (int k = 0; k < 16; ++k) {
      float o = koff[h * 16 + k];
      float a = kamp[h * 16 + k];
      float s = fabsf(kshp[h * 16 + k]);
      float d = o - rel;
      acc += a * __expf(-s * d * d);
    }
    scores[h * SCP + r] = acc;
  }
}

// ---------------------------------------------------------------- QKV GEMM
// C[m,n] = sum_k x[m,k] * w_in[n,k].  1-D grid 768, XCD-swizzled:
// xcd=bid&7 (m09: XCD = bid%8), each XCD owns m-tiles {xcd,8+xcd,16+xcd,24+xcd}
// (A strip stays hot in its L2), sweeps all 24 n-tiles per m-tile.
__global__ __launch_bounds__(256) void qkv_gemm_k(
    const short* __restrict__ A, const short* __restrict__ Bw,
    __hip_bfloat16* __restrict__ kbuf, __hip_bfloat16* __restrict__ vbufT,
    __hip_bfloat16* __restrict__ qbuf) {
  __shared__ __align__(16) short SM[128 * CTS];   // 34.8 KB; aliases As/Bs
  short* As = SM;
  short* Bs = SM + 128 * 64;
  const int tid  = threadIdx.x;
  const int lane = tid & 63;
  const int wv   = tid >> 6;
  const int l15  = lane & 15, quad = lane >> 4;
  const int wm = (wv & 1) * 64, wn = (wv >> 1) * 64;
  const int bid = blockIdx.x;
  const int xcd = bid & 7, g = bid >> 3;          // g in [0,96)
  const int xt  = g % 24;                         // n-tile
  const int yt  = (g / 24) * 8 + xcd;             // m-tile (XCD-owned strip)
  const int m0 = yt * 128, n0 = xt * 128;
  const int which = n0 >> 10;                     // 0=k, 1=v, 2=q

  f32x4 acc[4][4];
#pragma unroll
  for (int r = 0; r < 4; ++r)
#pragma unroll
    for (int c = 0; c < 4; ++c) acc[r][c] = (f32x4){0.f, 0.f, 0.f, 0.f};

  for (int kt = 0; kt < 16; ++kt) {
    const int k0 = kt * 64;
#pragma unroll
    for (int it = 0; it < 4; ++it) {
      const int e8  = it * 256 + tid;
      const int row = e8 >> 3;
      const int col = (e8 & 7) * 8;
      GLD(A + (size_t)(m0 + row) * DMODEL + k0 + col, &As[e8 * 8]);
      GLD(Bw + (size_t)(n0 + row) * DMODEL + k0 + col, &Bs[e8 * 8]);
    }
    __syncthreads();
#pragma unroll
    for (int ki = 0; ki < 64; ki += 32) {
      bf16x8 af[4], bfv[4];
#pragma unroll
      for (int r = 0; r < 4; ++r)
        af[r] = *(const bf16x8*)&As[(wm + r * 16 + l15) * 64 + ki + quad * 8];
#pragma unroll
      for (int c = 0; c < 4; ++c)
        bfv[c] = *(const bf16x8*)&Bs[(wn + c * 16 + l15) * 64 + ki + quad * 8];
#pragma unroll
      for (int r = 0; r < 4; ++r)
#pragma unroll
        for (int c = 0; c < 4; ++c)
          acc[r][c] = __builtin_amdgcn_mfma_f32_16x16x32_bf16(af[r], bfv[c], acc[r][c], 0, 0, 0);
    }
    __syncthreads();
  }

  // ---- epilogue: C/D layout m = wm+r*16+quad*4+g, n = wn+c*16+l15 ----
  const int bb  = m0 >> 11;
  const int llb = m0 & 2047;
  const int hhb = (n0 >> 6) & 15;
  if (which != 1) {
    const float qs = (which == 2) ? 0.125f : 1.0f;
#pragma unroll
    for (int r = 0; r < 4; ++r)
#pragma unroll
      for (int c = 0; c < 4; ++c)
#pragma unroll
        for (int gg = 0; gg < 4; ++gg)
          SM[(wm + r * 16 + quad * 4 + gg) * CTS + wn + c * 16 + l15] =
              f2bf_fast(acc[r][c][gg] * qs);
    __syncthreads();
    __hip_bfloat16* dst = (which == 0) ? kbuf : qbuf;
#pragma unroll
    for (int i = 0; i < 8; ++i) {
      const int cidx = i * 256 + tid;
      const int m = cidx >> 4, ch = cidx & 15;
      bf16x8 val = *(const bf16x8*)&SM[m * CTS + ch * 8];
      const int hh  = hhb + (ch >> 3);
      const int hd0 = (ch & 7) * 8;
      *(bf16x8*)&dst[(((size_t)bb * NH + hh) * SL + llb + m) * DH + hd0] = val;
    }
  } else {
#pragma unroll
    for (int r = 0; r < 4; ++r)
#pragma unroll
      for (int c = 0; c < 4; ++c) {
        bf16x4 pk;
#pragma unroll
        for (int gg = 0; gg < 4; ++gg) pk[gg] = f2bf_fast(acc[r][c][gg]);
        *(bf16x4*)&SM[(wn + c * 16 + l15) * CTS + wm + r * 16 + quad * 4] = pk;
      }
    __syncthreads();
#pragma unroll
    for (int i = 0; i < 8; ++i) {
      const int cidx = i * 256 + tid;
      const int n = cidx >> 4, ch = cidx & 15;
      bf16x8 val = *(const bf16x8*)&SM[n * CTS + ch * 8];
      const int hh = hhb + (n >> 6);
      const int hd = n & 63;
      *(bf16x8*)&vbufT[(((size_t)bb * NH + hh) * DH + hd) * SL + llb + ch * 8] = val;
    }
  }
}

// ---------------------------------------------------------------- attention
// (R9 structure; grid already XCD-friendly: all 32 q-tiles of a (b,h) land on
// XCD bh%8 -> K/V L2-hot.  This round: fast P pack + hoisted staging maps.)
__global__ __launch_bounds__(128, 2) void attn_k(
    const __hip_bfloat16* __restrict__ qbuf, const __hip_bfloat16* __restrict__ kbuf,
    const __hip_bfloat16* __restrict__ vbufT, const float* __restrict__ scores,
    float* __restrict__ out) {
  __shared__ __align__(16) short Ks[64 * 72];    // 9216 B
  __shared__ __align__(16) short Vs[64 * 72];    // 9216 B
  __shared__ __align__(16) float Bss[2112];      // 8448 B   => 26.9 KB total
  const int bh   = blockIdx.x;
  const int b    = bh >> 4, h = bh & 15;
  const int tid  = threadIdx.x;                  // 0..127
  const int lane = tid & 63;
  const int wv   = tid >> 6;                     // 0..1
  const int n32  = lane & 31, hf = lane >> 5;
  const int i0b  = blockIdx.y * 64;
  const int i0   = i0b + wv * 32;
  const __hip_bfloat16* qb = qbuf + (size_t)bh * SL * DH;
  const short* kb = (const short*)(kbuf + (size_t)bh * SL * DH);
  const short* vb = (const short*)(vbufT + (size_t)bh * DH * SL);
  const float* sc = scores + h * SCP;

  {
    const float* bsrc = sc + i0b;
#pragma unroll
    for (int i = 0; i < 4; ++i)
      GLD(bsrc + (size_t)(i * 128 + tid) * 4, &Bss[(i * 128 + tid) * 4]);
    if (tid < 16) GLD(bsrc + (size_t)(512 + tid) * 4, &Bss[(512 + tid) * 4]);
  }

  // hoisted 9-chunk staging map (shared by K and V; /9 done once)
  int rc[5], scnk[5];
#pragma unroll
  for (int i = 0; i < 5; ++i) {
    const int c = i * 128 + tid;
    rc[i] = c / 9; scnk[i] = (c - rc[i] * 9) * 8;
  }

  bf16x8 qf[4];
#pragma unroll
  for (int kc = 0; kc < 4; ++kc)
    qf[kc] = *(const bf16x8*)&qb[(size_t)(i0 + n32) * DH + kc * 16 + hf * 8];

  f32x16 ot[2];    // O^T: hd = dt*32 + (r&3)+8*(r>>2)+4*hf, qrow = n32
#pragma unroll
  for (int dt = 0; dt < 2; ++dt)
#pragma unroll
    for (int r = 0; r < 16; ++r) ot[dt][r] = 0.f;
  float lsum = 0.f;

  for (int j0 = 0; j0 < SL; j0 += 64) {
    const short* ksrc = kb + (size_t)j0 * DH;
#pragma unroll
    for (int i = 0; i < 4; ++i)
      GLD(ksrc + (size_t)rc[i] * DH + scnk[i], &Ks[(i * 128 + tid) * 8]);
    if (tid < 64) GLD(ksrc + (size_t)rc[4] * DH + scnk[4], &Ks[(512 + tid) * 8]);
#pragma unroll
    for (int i = 0; i < 4; ++i)
      GLD(vb + (size_t)rc[i] * SL + j0 + scnk[i], &Vs[(i * 128 + tid) * 8]);
    if (tid < 64) GLD(vb + (size_t)rc[4] * SL + j0 + scnk[4], &Vs[(512 + tid) * 8]);
    __syncthreads();

#pragma unroll
    for (int kt = 0; kt < 2; ++kt) {
      f32x16 st;
#pragma unroll
      for (int r = 0; r < 16; ++r) st[r] = 0.f;
#pragma unroll
      for (int kc = 0; kc < 4; ++kc) {
        bf16x8 kf = *(const bf16x8*)&Ks[(kt * 32 + n32) * 72 + kc * 16 + hf * 8];
        st = __builtin_amdgcn_mfma_f32_32x32x16_bf16(kf, qf[kc], st, 0, 0, 0);
      }
      bf16x4 pk[4];
      const int tb0 = wv * 32 + n32 - j0 - kt * 32 - 4 * hf + 2047;
#pragma unroll
      for (int g = 0; g < 4; ++g) {
        const int tb = tb0 - 8 * g;
#pragma unroll
        for (int i = 0; i < 4; ++i) {
          const float p = __expf(st[g * 4 + i] + Bss[tb - i]);
          lsum += p;
          pk[g][i] = f2bf_fast(p);
        }
      }
      long long s0 = hf ? bf4_to_ll(pk[0]) : bf4_to_ll(pk[1]);
      bf16x4 r0 = ll_to_bf4(__shfl_xor(s0, 32));
      bf16x8 pf0 = hf == 0 ? __builtin_shufflevector(pk[0], r0, 0, 1, 2, 3, 4, 5, 6, 7)
                           : __builtin_shufflevector(r0, pk[1], 0, 1, 2, 3, 4, 5, 6, 7);
      long long s1 = hf ? bf4_to_ll(pk[2]) : bf4_to_ll(pk[3]);
      bf16x4 r1 = ll_to_bf4(__shfl_xor(s1, 32));
      bf16x8 pf1 = hf == 0 ? __builtin_shufflevector(pk[2], r1, 0, 1, 2, 3, 4, 5, 6, 7)
                           : __builtin_shufflevector(r1, pk[3], 0, 1, 2, 3, 4, 5, 6, 7);
#pragma unroll
      for (int dt = 0; dt < 2; ++dt) {
        const short* vr = &Vs[(dt * 32 + n32) * 72 + kt * 32];
        bf16x8 vf0 = *(const bf16x8*)&vr[hf * 8];
        bf16x8 vf1 = *(const bf16x8*)&vr[16 + hf * 8];
        ot[dt] = __builtin_amdgcn_mfma_f32_32x32x16_bf16(vf0, pf0, ot[dt], 0, 0, 0);
        ot[dt] = __builtin_amdgcn_mfma_f32_32x32x16_bf16(vf1, pf1, ot[dt], 0, 0, 0);
      }
    }
    __syncthreads();
  }

  lsum += __shfl_xor(lsum, 32);
  const float inv = 1.f / lsum;
  float* orow = out + (((size_t)b * SL + i0 + n32) * NH + h) * DH;
#pragma unroll
  for (int dt = 0; dt < 2; ++dt)
#pragma unroll
    for (int g = 0; g < 4; ++g) {
      f32x4 v;
#pragma unroll
      for (int i = 0; i < 4; ++i) v[i] = ot[dt][g * 4 + i] * inv;
      *(f32x4*)&orow[dt * 32 + 8 * g + 4 * hf] = v;
    }
}

// ---------------------------------------------------------------- launch
extern "C" void kernel_launch(void* const* d_in, const int* in_sizes, int n_in,
                              void* d_out, int out_size, void* d_ws, size_t ws_size,
                              hipStream_t stream) {
  const float* x    = (const float*)d_in[0];   // (B,L,D) fp32
  const float* w    = (const float*)d_in[1];   // (3D,D) fp32
  const float* koff = (const float*)d_in[2];   // (H,K) fp32
  const float* kamp = (const float*)d_in[3];
  const float* kshp = (const float*)d_in[4];
  float* out = (float*)d_out;                  // (B,L,D) fp32

  const size_t per = (size_t)NB * NH * SL * DH;               // 4,194,304 elems
  const size_t nx  = (size_t)NB * SL * DMODEL;                // 4,194,304
  const size_t nw  = (size_t)3 * DMODEL * DMODEL;             // 3,145,728

  __hip_bfloat16* kbuf  = (__hip_bfloat16*)d_ws;              // 8 MB
  __hip_bfloat16* vbufT = kbuf + per;                         // 8 MB
  __hip_bfloat16* qbuf  = vbufT + per;                        // 8 MB
  float* scores = (float*)(qbuf + per);                       // 256 KB
  short* xbf    = (short*)(scores + (size_t)NH * SCP);        // 8 MB
  short* wbf    = xbf + nx;                                   // 6 MB   => ~38.3 MB total

  prep_k<<<7424, 256, 0, stream>>>(x, w, koff, kamp, kshp, xbf, wbf, scores);
  qkv_gemm_k<<<768, 256, 0, stream>>>(xbf, wbf, kbuf, vbufT, qbuf);
  attn_k<<<dim3(NB * NH, SL / 64), 128, 0, stream>>>(qbuf, kbuf, vbufT, scores, out);
}

// Round 12
// 195.561 us; speedup vs baseline: 1.0350x; 1.0350x over previous
//
#include <hip/hip_runtime.h>
#include <hip/hip_bf16.h>
#include <stdint.h>
#include <stddef.h>

// Problem: B=2, L=2048, D=1024, H=16, HD=64.
// Inputs FP32, output FP32.  Internal pipeline bf16 MFMA.
// R12: (a) attn reverted verbatim to R10 (R11's hoisted maps + pack rewrite
// perturbed the schedule: 77->81.6us).  (b) gemm re-tiled 128x64: XCD swizzle
// was neutral -> gemm is drain-stall bound at 3 blocks/CU, not L3-BW bound.
// 24KB LDS (epilogue unioned) -> 6 blocks/CU, grid 1536: 2x concurrent
// drains.  N-tile = one head exactly -> simpler epilogue.

#define NB     2
#define NH     16
#define SL     2048
#define DH     64
#define DMODEL 1024
#define SCP    4096   // padded scores row stride (floats); 4095 real

typedef __attribute__((ext_vector_type(8)))  short bf16x8;
typedef __attribute__((ext_vector_type(4)))  short bf16x4;
typedef __attribute__((ext_vector_type(4)))  float f32x4;
typedef __attribute__((ext_vector_type(16))) float f32x16;

static __device__ __forceinline__ short f2bf(float x) {   // RNE
  __hip_bfloat16 h = __float2bfloat16(x);
  return *reinterpret_cast<short*>(&h);
}
static __device__ __forceinline__ short f2bf_fast(float x) {  // round-half-up
  union { float f; uint32_t u; } v; v.f = x;
  return (short)((v.u + 0x8000u) >> 16);
}
static __device__ __forceinline__ long long bf4_to_ll(bf16x4 v) {
  long long r; __builtin_memcpy(&r, &v, 8); return r;
}
static __device__ __forceinline__ bf16x4 ll_to_bf4(long long v) {
  bf16x4 r; __builtin_memcpy(&r, &v, 8); return r;
}
#define GLD(g, l) __builtin_amdgcn_global_load_lds( \
    (const __attribute__((address_space(1))) void*)(g), \
    (__attribute__((address_space(3))) void*)(l), 16, 0, 0)

// ---------------------------------------------------- prep: cvt x, cvt w, bias
__global__ __launch_bounds__(256) void prep_k(
    const float* __restrict__ x, const float* __restrict__ w,
    const float* __restrict__ koff, const float* __restrict__ kamp,
    const float* __restrict__ kshp,
    short* __restrict__ xbf, short* __restrict__ wbf,
    float* __restrict__ scores) {
  const int bx = blockIdx.x, tid = threadIdx.x;
  if (bx < 7168) {
    const float* src = (bx < 4096) ? x : w;
    short* dst       = (bx < 4096) ? xbf : wbf;
    const int i      = (bx < 4096 ? bx : bx - 4096) * 256 + tid;
    float4 a = *(const float4*)(src + (size_t)i * 4);
    bf16x4 o;
    o.x = f2bf(a.x); o.y = f2bf(a.y); o.z = f2bf(a.z); o.w = f2bf(a.w);
    *(bf16x4*)(dst + (size_t)i * 4) = o;
  } else {
    const int idx = bx - 7168;
    const int h = idx >> 4;
    const int r = (idx & 15) * 256 + tid;
    if (r >= 4095) return;
    float rel = (float)(r - (SL - 1));
    float acc = 0.f;
#pragma unroll
    for (int k = 0; k < 16; ++k) {
      float o = koff[h * 16 + k];
      float a = kamp[h * 16 + k];
      float s = fabsf(kshp[h * 16 + k]);
      float d = o - rel;
      acc += a * __expf(-s * d * d);
    }
    scores[h * SCP + r] = acc;
  }
}

// ---------------------------------------------------------------- QKV GEMM
// C[m,n] = sum_k x[m,k] * w_in[n,k].  Tile 128x64, BK=64, 16 steps.
// Grid (48 n-tiles, 32 m-tiles) = 1536 blocks = 6/CU (LDS 24KB).
// Each n-tile = one head's 64 cols; slot = xt>>4 (0=k,1=v,2=q).
__global__ __launch_bounds__(256) void qkv_gemm_k(
    const short* __restrict__ A, const short* __restrict__ Bw,
    __hip_bfloat16* __restrict__ kbuf, __hip_bfloat16* __restrict__ vbufT,
    __hip_bfloat16* __restrict__ qbuf) {
  __shared__ __align__(16) short SM[12288];       // 24 KB; As | Bs, reused by epilogue
  short* As = SM;                                  // 128*64 shorts
  short* Bs = SM + 8192;                           // 64*64 shorts
  const int tid  = threadIdx.x;
  const int lane = tid & 63;
  const int wv   = tid >> 6;
  const int l15  = lane & 15, quad = lane >> 4;
  const int wm = (wv & 1) * 64, wn = (wv >> 1) * 32;
  const int xt = blockIdx.x, yt = blockIdx.y;
  const int m0 = yt * 128, n0 = xt * 64;
  const int which = xt >> 4;                       // 0=k, 1=v, 2=q
  const int hh    = xt & 15;                       // the head this tile serves

  f32x4 acc[4][2];
#pragma unroll
  for (int r = 0; r < 4; ++r)
#pragma unroll
    for (int c = 0; c < 2; ++c) acc[r][c] = (f32x4){0.f, 0.f, 0.f, 0.f};

  for (int kt = 0; kt < 16; ++kt) {
    const int k0 = kt * 64;
#pragma unroll
    for (int it = 0; it < 4; ++it) {               // A: 1024 chunks
      const int e8  = it * 256 + tid;
      GLD(A + (size_t)(m0 + (e8 >> 3)) * DMODEL + k0 + (e8 & 7) * 8, &As[e8 * 8]);
    }
#pragma unroll
    for (int it = 0; it < 2; ++it) {               // B: 512 chunks
      const int e8  = it * 256 + tid;
      GLD(Bw + (size_t)(n0 + (e8 >> 3)) * DMODEL + k0 + (e8 & 7) * 8, &Bs[e8 * 8]);
    }
    __syncthreads();
#pragma unroll
    for (int ki = 0; ki < 64; ki += 32) {
      bf16x8 af[4], bfv[2];
#pragma unroll
      for (int r = 0; r < 4; ++r)
        af[r] = *(const bf16x8*)&As[(wm + r * 16 + l15) * 64 + ki + quad * 8];
#pragma unroll
      for (int c = 0; c < 2; ++c)
        bfv[c] = *(const bf16x8*)&Bs[(wn + c * 16 + l15) * 64 + ki + quad * 8];
#pragma unroll
      for (int r = 0; r < 4; ++r)
#pragma unroll
        for (int c = 0; c < 2; ++c)
          acc[r][c] = __builtin_amdgcn_mfma_f32_16x16x32_bf16(af[r], bfv[c], acc[r][c], 0, 0, 0);
    }
    __syncthreads();
  }

  // ---- epilogue: C/D layout m = wm+r*16+quad*4+g, n = wn+c*16+l15 ----
  const int bb  = m0 >> 11;
  const int llb = m0 & 2047;
  if (which != 1) {
    // k/q: LDS [m][n] stride 72 -> b128 row reads -> 16B coalesced stores
    const float qs = (which == 2) ? 0.125f : 1.0f;
#pragma unroll
    for (int r = 0; r < 4; ++r)
#pragma unroll
      for (int c = 0; c < 2; ++c)
#pragma unroll
        for (int gg = 0; gg < 4; ++gg)
          SM[(wm + r * 16 + quad * 4 + gg) * 72 + wn + c * 16 + l15] =
              f2bf_fast(acc[r][c][gg] * qs);
    __syncthreads();
    __hip_bfloat16* dst = (which == 0) ? kbuf : qbuf;
#pragma unroll
    for (int i = 0; i < 4; ++i) {
      const int cidx = i * 256 + tid;              // 1024 16B chunks
      const int m = cidx >> 3, ch = cidx & 7;
      bf16x8 val = *(const bf16x8*)&SM[m * 72 + ch * 8];
      *(bf16x8*)&dst[(((size_t)bb * NH + hh) * SL + llb + m) * DH + ch * 8] = val;
    }
  } else {
    // v: LDS [n][m] stride 136 -> b128 row reads -> [hd][l] 16B stores
#pragma unroll
    for (int r = 0; r < 4; ++r)
#pragma unroll
      for (int c = 0; c < 2; ++c) {
        bf16x4 pk;
#pragma unroll
        for (int gg = 0; gg < 4; ++gg) pk[gg] = f2bf_fast(acc[r][c][gg]);
        *(bf16x4*)&SM[(wn + c * 16 + l15) * 136 + wm + r * 16 + quad * 4] = pk;
      }
    __syncthreads();
#pragma unroll
    for (int i = 0; i < 4; ++i) {
      const int cidx = i * 256 + tid;              // 1024 16B chunks
      const int n = cidx >> 4, ch = cidx & 15;
      bf16x8 val = *(const bf16x8*)&SM[n * 136 + ch * 8];
      *(bf16x8*)&vbufT[(((size_t)bb * NH + hh) * DH + n) * SL + llb + ch * 8] = val;
    }
  }
}

// ---------------------------------------------------------------- attention
// (verbatim R10 — 76.5-77us; R11's "optimizations" regressed it)
__global__ __launch_bounds__(128, 2) void attn_k(
    const __hip_bfloat16* __restrict__ qbuf, const __hip_bfloat16* __restrict__ kbuf,
    const __hip_bfloat16* __restrict__ vbufT, const float* __restrict__ scores,
    float* __restrict__ out) {
  __shared__ __align__(16) short Ks[64 * 72];    // 9216 B
  __shared__ __align__(16) short Vs[64 * 72];    // 9216 B
  __shared__ __align__(16) float Bss[2112];      // 8448 B   => 26.9 KB total
  const int bh   = blockIdx.x;
  const int b    = bh >> 4, h = bh & 15;
  const int tid  = threadIdx.x;                  // 0..127
  const int lane = tid & 63;
  const int wv   = tid >> 6;                     // 0..1
  const int n32  = lane & 31, hf = lane >> 5;
  const int i0b  = blockIdx.y * 64;
  const int i0   = i0b + wv * 32;
  const __hip_bfloat16* qb = qbuf + (size_t)bh * SL * DH;
  const short* kb = (const short*)(kbuf + (size_t)bh * SL * DH);
  const short* vb = (const short*)(vbufT + (size_t)bh * DH * SL);
  const float* sc = scores + h * SCP;

  {
    const float* bsrc = sc + i0b;
#pragma unroll
    for (int i = 0; i < 4; ++i)
      GLD(bsrc + (size_t)(i * 128 + tid) * 4, &Bss[(i * 128 + tid) * 4]);
    if (tid < 16) GLD(bsrc + (size_t)(512 + tid) * 4, &Bss[(512 + tid) * 4]);
  }

  bf16x8 qf[4];
#pragma unroll
  for (int kc = 0; kc < 4; ++kc)
    qf[kc] = *(const bf16x8*)&qb[(size_t)(i0 + n32) * DH + kc * 16 + hf * 8];

  f32x16 ot[2];    // O^T: hd = dt*32 + (r&3)+8*(r>>2)+4*hf, qrow = n32
#pragma unroll
  for (int dt = 0; dt < 2; ++dt)
#pragma unroll
    for (int r = 0; r < 16; ++r) ot[dt][r] = 0.f;
  float lsum = 0.f;

  for (int j0 = 0; j0 < SL; j0 += 64) {
    {
      const short* ksrc = kb + (size_t)j0 * DH;
#pragma unroll
      for (int i = 0; i < 4; ++i) {
        int c = i * 128 + tid; int r = c / 9, s = c - r * 9;
        GLD(ksrc + (size_t)r * DH + s * 8, &Ks[c * 8]);
      }
      if (tid < 64) {
        int c = 512 + tid; int r = c / 9, s = c - r * 9;
        GLD(ksrc + (size_t)r * DH + s * 8, &Ks[c * 8]);
      }
    }
    {
#pragma unroll
      for (int i = 0; i < 4; ++i) {
        int c = i * 128 + tid; int r = c / 9, s = c - r * 9;
        GLD(vb + (size_t)r * SL + j0 + s * 8, &Vs[c * 8]);
      }
      if (tid < 64) {
        int c = 512 + tid; int r = c / 9, s = c - r * 9;
        GLD(vb + (size_t)r * SL + j0 + s * 8, &Vs[c * 8]);
      }
    }
    __syncthreads();

#pragma unroll
    for (int kt = 0; kt < 2; ++kt) {
      f32x16 st;
#pragma unroll
      for (int r = 0; r < 16; ++r) st[r] = 0.f;
#pragma unroll
      for (int kc = 0; kc < 4; ++kc) {
        bf16x8 kf = *(const bf16x8*)&Ks[(kt * 32 + n32) * 72 + kc * 16 + hf * 8];
        st = __builtin_amdgcn_mfma_f32_32x32x16_bf16(kf, qf[kc], st, 0, 0, 0);
      }
      bf16x4 pk[4];
      const int tb0 = wv * 32 + n32 - j0 - kt * 32 - 4 * hf + 2047;
#pragma unroll
      for (int g = 0; g < 4; ++g) {
        const int tb = tb0 - 8 * g;
#pragma unroll
        for (int i = 0; i < 4; ++i) {
          const float p = __expf(st[g * 4 + i] + Bss[tb - i]);
          lsum += p;
          pk[g][i] = f2bf_fast(p);
        }
      }
      long long s0 = hf ? bf4_to_ll(pk[0]) : bf4_to_ll(pk[1]);
      bf16x4 r0 = ll_to_bf4(__shfl_xor(s0, 32));
      bf16x8 pf0 = hf == 0 ? __builtin_shufflevector(pk[0], r0, 0, 1, 2, 3, 4, 5, 6, 7)
                           : __builtin_shufflevector(r0, pk[1], 0, 1, 2, 3, 4, 5, 6, 7);
      long long s1 = hf ? bf4_to_ll(pk[2]) : bf4_to_ll(pk[3]);
      bf16x4 r1 = ll_to_bf4(__shfl_xor(s1, 32));
      bf16x8 pf1 = hf == 0 ? __builtin_shufflevector(pk[2], r1, 0, 1, 2, 3, 4, 5, 6, 7)
                           : __builtin_shufflevector(r1, pk[3], 0, 1, 2, 3, 4, 5, 6, 7);
#pragma unroll
      for (int dt = 0; dt < 2; ++dt) {
        const short* vr = &Vs[(dt * 32 + n32) * 72 + kt * 32];
        bf16x8 vf0 = *(const bf16x8*)&vr[hf * 8];
        bf16x8 vf1 = *(const bf16x8*)&vr[16 + hf * 8];
        ot[dt] = __builtin_amdgcn_mfma_f32_32x32x16_bf16(vf0, pf0, ot[dt], 0, 0, 0);
        ot[dt] = __builtin_amdgcn_mfma_f32_32x32x16_bf16(vf1, pf1, ot[dt], 0, 0, 0);
      }
    }
    __syncthreads();
  }

  lsum += __shfl_xor(lsum, 32);
  const float inv = 1.f / lsum;
  float* orow = out + (((size_t)b * SL + i0 + n32) * NH + h) * DH;
#pragma unroll
  for (int dt = 0; dt < 2; ++dt)
#pragma unroll
    for (int g = 0; g < 4; ++g) {
      f32x4 v;
#pragma unroll
      for (int i = 0; i < 4; ++i) v[i] = ot[dt][g * 4 + i] * inv;
      *(f32x4*)&orow[dt * 32 + 8 * g + 4 * hf] = v;
    }
}

// ---------------------------------------------------------------- launch
extern "C" void kernel_launch(void* const* d_in, const int* in_sizes, int n_in,
                              void* d_out, int out_size, void* d_ws, size_t ws_size,
                              hipStream_t stream) {
  const float* x    = (const float*)d_in[0];   // (B,L,D) fp32
  const float* w    = (const float*)d_in[1];   // (3D,D) fp32
  const float* koff = (const float*)d_in[2];   // (H,K) fp32
  const float* kamp = (const float*)d_in[3];
  const float* kshp = (const float*)d_in[4];
  float* out = (float*)d_out;                  // (B,L,D) fp32

  const size_t per = (size_t)NB * NH * SL * DH;               // 4,194,304 elems
  const size_t nx  = (size_t)NB * SL * DMODEL;                // 4,194,304
  const size_t nw  = (size_t)3 * DMODEL * DMODEL;             // 3,145,728

  __hip_bfloat16* kbuf  = (__hip_bfloat16*)d_ws;              // 8 MB
  __hip_bfloat16* vbufT = kbuf + per;                         // 8 MB
  __hip_bfloat16* qbuf  = vbufT + per;                        // 8 MB
  float* scores = (float*)(qbuf + per);                       // 256 KB
  short* xbf    = (short*)(scores + (size_t)NH * SCP);        // 8 MB
  short* wbf    = xbf + nx;                                   // 6 MB   => ~38.3 MB total

  prep_k<<<7424, 256, 0, stream>>>(x, w, koff, kamp, kshp, xbf, wbf, scores);
  qkv_gemm_k<<<dim3(48, 32), 256, 0, stream>>>(xbf, wbf, kbuf, vbufT, qbuf);
  attn_k<<<dim3(NB * NH, SL / 64), 128, 0, stream>>>(qbuf, kbuf, vbufT, scores, out);
}